// Round 8
// baseline (294.580 us; speedup 1.0000x reference)
//
#include <hip/hip_runtime.h>

#define N_NODES 10000
#define E_EDGES 320000
#define F_IN    256
#define F_PROJ  200

typedef float vfloat4 __attribute__((ext_vector_type(4)));

#define N4_TOTAL 25000000L          // ev / edge_attr in float4s
#define S1_SPLIT 4000000L           // float4s nt-copied in K1 (128 MB traffic)

#define K1_PROJ_BLOCKS 1250
#define K1_COPY_BLOCKS 768
#define A_BLOCKS    2048
#define A_CHUNK     40              // 2048*4 waves * 40 >= 320000
#define AGG_BLOCKS  160
#define AGG_N4      (N_NODES * F_IN / 4)     // 640000
#define AGG_PER_BLK (AGG_N4 / AGG_BLOCKS)    // 4000
#define K3_BLOCKS   4096

// workspace layout (5.33 MB)
#define WS_P      0L           // 4,000,000  (bf16 P)
#define WS_EXP    4000000L     // 1,280,000  (expalpha)
#define WS_FLAGS  5280000L     // 40,000
#define WS_SUM    5320000L     // 16

__device__ __forceinline__ unsigned short f32_to_bf16(float f) {
    unsigned int u = __float_as_uint(f);
    u += 0x7FFFu + ((u >> 16) & 1u);
    return (unsigned short)(u >> 16);
}
__device__ __forceinline__ float bf16_to_f32(unsigned short b) {
    return __uint_as_float(((unsigned int)b) << 16);
}

// ---- K1: proj + flag-scan (1250 blocks) ∥ nt-copy [0,S1) (768 blocks) -------
// nt here: runs BEFORE alpha, must not evict P / pollute for K2's gathers.
__global__ __launch_bounds__(256) void k1_proj_flags_copy(
        const float* __restrict__ x, const float* __restrict__ W,
        unsigned short* __restrict__ P, const int* __restrict__ ei,
        int* __restrict__ flags,
        const vfloat4* __restrict__ csrc, vfloat4* __restrict__ cdst) {
    int bid = blockIdx.x, tid = threadIdx.x;
    if (bid >= K1_PROJ_BLOCKS) {
        long i = (long)(bid - K1_PROJ_BLOCKS) * 256 + tid;
        const long stride = (long)K1_COPY_BLOCKS * 256;
        for (; i < S1_SPLIT; i += stride) {
            vfloat4 v = __builtin_nontemporal_load(csrc + i);
            __builtin_nontemporal_store(v, cdst + i);
        }
        return;
    }
    int gt = bid * 256 + tid;                  // 1250*256 == E exactly
    flags[ei[E_EDGES + gt]] = 1;               // racy same-value store: fine

    __shared__ float xs[8][F_IN];
    int n0 = bid * 8;
    for (int i = tid; i < 8 * F_IN / 4; i += 256)
        ((float4*)xs)[i] = ((const float4*)(x + (long)n0 * F_IN))[i];
    __syncthreads();
    int j = tid;
    if (j >= F_PROJ) return;
    float acc[8] = {0.f,0.f,0.f,0.f,0.f,0.f,0.f,0.f};
    for (int k = 0; k < F_IN; ++k) {
        float w = W[k * F_PROJ + j];
        #pragma unroll
        for (int r = 0; r < 8; ++r) acc[r] += xs[r][k] * w;
    }
    #pragma unroll
    for (int r = 0; r < 8; ++r) P[(long)(n0 + r) * F_PROJ + j] = f32_to_bf16(acc[r]);
}

// ---- K2: alpha (2048 blocks) ∥ agg (160 blocks) — pure, no copy mixing ------
__global__ __launch_bounds__(256) void k2_alpha_agg(
        const int* __restrict__ ei, const unsigned short* __restrict__ P,
        const float* __restrict__ Watt, const float* __restrict__ batt,
        float* __restrict__ expalpha, float* __restrict__ sumbuf,
        const int* __restrict__ flags, const float4* __restrict__ x4,
        float4* __restrict__ agg4) {
    int bid = blockIdx.x, tid = threadIdx.x;
    if (bid < A_BLOCKS) {
        __shared__ float bsum;
        if (tid == 0) bsum = 0.f;
        __syncthreads();
        int wid  = bid * 4 + (tid >> 6);
        int lane = tid & 63;
        float4 w4 = make_float4(0.f, 0.f, 0.f, 0.f);
        if (lane < 50) w4 = ((const float4*)Watt)[lane];
        float bias = batt[0];
        int e0 = wid * A_CHUNK;
        int e1 = min(e0 + A_CHUNK, E_EDGES);
        float lsum = 0.f;
        for (int e = e0; e < e1; ++e) {
            int s = ei[e];
            int d = ei[E_EDGES + e];
            float acc = 0.f;
            if (lane < 50) {
                uint2 us = *(const uint2*)(P + (long)s * F_PROJ + lane * 4);
                uint2 ud = *(const uint2*)(P + (long)d * F_PROJ + lane * 4);
                acc = fabsf(bf16_to_f32((unsigned short)(ud.x & 0xFFFF)) -
                            bf16_to_f32((unsigned short)(us.x & 0xFFFF))) * w4.x
                    + fabsf(bf16_to_f32((unsigned short)(ud.x >> 16)) -
                            bf16_to_f32((unsigned short)(us.x >> 16))) * w4.y
                    + fabsf(bf16_to_f32((unsigned short)(ud.y & 0xFFFF)) -
                            bf16_to_f32((unsigned short)(us.y & 0xFFFF))) * w4.z
                    + fabsf(bf16_to_f32((unsigned short)(ud.y >> 16)) -
                            bf16_to_f32((unsigned short)(us.y >> 16))) * w4.w;
            }
            #pragma unroll
            for (int off = 32; off; off >>= 1) acc += __shfl_down(acc, off);
            if (lane == 0) {
                float ea = expf(fmaxf(acc + bias, 0.f));   // alpha in [0,~6]
                expalpha[e] = ea;
                lsum += ea;
            }
        }
        if (lane == 0) atomicAdd(&bsum, lsum);
        __syncthreads();
        if (tid == 0) atomicAdd(sumbuf, bsum);
        return;
    }
    long base = (long)(bid - A_BLOCKS) * AGG_PER_BLK;
    for (int i = tid; i < AGG_PER_BLK; i += 256) {
        long i4 = base + i;
        float4 v = x4[i4];
        if (!flags[i4 >> 6]) v = make_float4(0.f, 0.f, 0.f, 0.f);
        agg4[i4] = v;
    }
}

// ---- K3: pure CACHED copy [S1, N4) — the nt-vs-cached experiment ------------
// Alpha is done: LLC pollution is harmless. Plain loads/stores, 2x unroll.
__global__ __launch_bounds__(256) void k3_copy(
        const vfloat4* __restrict__ src, vfloat4* __restrict__ dst) {
    long i = S1_SPLIT + (long)blockIdx.x * 256 + threadIdx.x;
    const long stride = (long)K3_BLOCKS * 256;
    for (; i + stride < N4_TOTAL; i += 2 * stride) {
        vfloat4 a = src[i];
        vfloat4 b = src[i + stride];
        dst[i] = a;
        dst[i + stride] = b;
    }
    if (i < N4_TOTAL) dst[i] = src[i];
}

// ---- K4: scatter a into ev (after full copy) --------------------------------
__global__ __launch_bounds__(256) void k4_scatter(
        const int* __restrict__ ei, const float* __restrict__ expalpha,
        const float* __restrict__ sumbuf, float* __restrict__ ev) {
    int e = blockIdx.x * 256 + threadIdx.x;
    if (e >= E_EDGES) return;
    float a = expalpha[e] / sumbuf[0];
    int s = ei[e], d = ei[E_EDGES + e];
    ev[(long)s * N_NODES + d] = a;
    ev[(long)d * N_NODES + s] = a;
}

// ================= host ======================================================
extern "C" void kernel_launch(void* const* d_in, const int* in_sizes, int n_in,
                              void* d_out, int out_size, void* d_ws, size_t ws_size,
                              hipStream_t stream) {
    (void)in_sizes; (void)n_in; (void)out_size; (void)ws_size;
    const float* x         = (const float*)d_in[0];
    const float* edge_attr = (const float*)d_in[1];
    const int*   ei        = (const int*)d_in[2];
    const float* W_proj    = (const float*)d_in[3];
    // d_in[4] = b_proj: cancels in p_i - p_j, unused
    const float* W_att     = (const float*)d_in[5];
    const float* b_att     = (const float*)d_in[6];

    float* agg = (float*)d_out;
    float* ev  = (float*)d_out + (long)N_NODES * F_IN;
    char* ws = (char*)d_ws;

    unsigned short* P = (unsigned short*)(ws + WS_P);
    float* expalpha   = (float*)(ws + WS_EXP);
    int*   flags      = (int*)(ws + WS_FLAGS);
    float* sumbuf     = (float*)(ws + WS_SUM);

    hipMemsetAsync(ws + WS_FLAGS, 0, 40016, stream);

    k1_proj_flags_copy<<<K1_PROJ_BLOCKS + K1_COPY_BLOCKS, 256, 0, stream>>>(
        x, W_proj, P, ei, flags, (const vfloat4*)edge_attr, (vfloat4*)ev);

    k2_alpha_agg<<<A_BLOCKS + AGG_BLOCKS, 256, 0, stream>>>(
        ei, P, W_att, b_att, expalpha, sumbuf, flags,
        (const float4*)x, (float4*)agg);

    k3_copy<<<K3_BLOCKS, 256, 0, stream>>>(
        (const vfloat4*)edge_attr, (vfloat4*)ev);

    k4_scatter<<<(E_EDGES + 255) / 256, 256, 0, stream>>>(
        ei, expalpha, sumbuf, ev);
}